// Round 4
// baseline (195.417 us; speedup 1.0000x reference)
//
#include <hip/hip_runtime.h>
#include <hip/hip_bf16.h>
#include <stdint.h>

#define BATCH   32768
#define NBLK    8
#define BIN     256
#define BOUT    256
#define XCOLS   2048      // NBLK*BIN
#define BM      64
#define BK      64
#define KSTEPS  4         // BIN/BK

typedef short bf16x8_t __attribute__((ext_vector_type(8)));
typedef float f32x4_t  __attribute__((ext_vector_type(4)));

// ---------------- prepass: W fp32 [8][256][256] -> frag-linear bf16 ----------------
// Layout so each wave's B-fragment load is a coalesced 16B/lane global load:
//   elem index = ((((n*4 + kk)*2 + ks)*16 + wgrp)*64 + lane)*8 + j
// where wgrp = o>>4 (= wave*4+nf), lane = fq*16+fr, o = wgrp*16 + (lane&15),
//       k = kk*64 + ks*32 + (lane>>4)*8 + j.
__global__ __launch_bounds__(256) void prep_w_kernel(
    const float* __restrict__ W, unsigned short* __restrict__ Wsz) {
  int idx = blockIdx.x * 256 + threadIdx.x;   // 0 .. 2^19-1
  int j    = idx & 7;
  int l    = (idx >> 3) & 63;
  int wgrp = (idx >> 9) & 15;
  int ks   = (idx >> 13) & 1;
  int kk   = (idx >> 14) & 3;
  int n    = idx >> 16;
  int o = wgrp * 16 + (l & 15);
  int k = kk * 64 + ks * 32 + (l >> 4) * 8 + j;
  float v = W[((size_t)(n * 256 + o) * 256) + k];
  uint32_t bits = __builtin_bit_cast(uint32_t, v);
  // round-to-nearest-even
  Wsz[idx] = (unsigned short)((bits + 0x7FFFu + ((bits >> 16) & 1u)) >> 16);
}

// ---------------- main kernel: LDS-free, barrier-free ----------------
// Each WG: 64 rows x full 256-col block n. Wave w covers cols w*64..w*64+63.
// A-fragments loaded straight from global (L1 dedups the 4-wave duplication);
// B-fragments from the frag-linear prepass buffer (L2-resident, coalesced).
__global__ __launch_bounds__(256, 4) void blocklinear_kernel(
    const float* __restrict__ x, const unsigned short* __restrict__ Wsz,
    const float* __restrict__ bias, float* __restrict__ y) {
  const int wgid = blockIdx.x;
  const int n    = wgid & 7;        // block id fastest
  const int mt   = wgid >> 3;
  const int m0   = mt * BM;
  const int tid  = threadIdx.x;
  const int wave = tid >> 6;
  const int lane = tid & 63;
  const int fr   = lane & 15;
  const int fq   = lane >> 4;

  f32x4_t acc[4][4];
#pragma unroll
  for (int mf = 0; mf < 4; ++mf)
#pragma unroll
    for (int nf = 0; nf < 4; ++nf)
      acc[mf][nf] = (f32x4_t){0.f, 0.f, 0.f, 0.f};

  // per-lane x base: row (m0+fr), col n*256 + fq*8. A-frag (mf,kk,ks,h) is at
  // + mf*16*XCOLS + kk*64 + ks*32 + h*4   (h = 0/1 -> two dwordx4 per frag)
  const float* xr0 = x + (size_t)(m0 + fr) * XCOLS + n * BIN + fq * 8;
  // per-lane W base for this wave (frag-linear layout; offsets compile-time)
  const unsigned short* wl =
      Wsz + (size_t)n * (KSTEPS * 2 * 16 * 64 * 8) + ((wave * 4) << 9) + (lane << 3);

#pragma unroll
  for (int kk = 0; kk < KSTEPS; ++kk) {
    // ---- B fragments: 8 coalesced 16B/lane loads from L2 ----
    bf16x8_t bfrag[2][4];
#pragma unroll
    for (int ks = 0; ks < 2; ++ks)
#pragma unroll
      for (int nf = 0; nf < 4; ++nf)
        bfrag[ks][nf] = *(const bf16x8_t*)&wl[(((kk * 2 + ks) * 16 + nf) << 9)];

    // ---- A fragments direct from global, pack fp32->bf16 in-register ----
#pragma unroll
    for (int mf = 0; mf < 4; ++mf) {
      const float* xp = xr0 + (size_t)(mf * 16) * XCOLS + kk * BK;
#pragma unroll
      for (int ks = 0; ks < 2; ++ks) {
        union { f32x4_t f; uint32_t u[4]; } A0, A1;
        A0.f = *(const f32x4_t*)(xp + ks * 32);
        A1.f = *(const f32x4_t*)(xp + ks * 32 + 4);
        union { uint32_t u[4]; bf16x8_t v; } af;
        af.u[0] = ((A0.u[0] + 0x8000u) >> 16) | ((A0.u[1] + 0x8000u) & 0xFFFF0000u);
        af.u[1] = ((A0.u[2] + 0x8000u) >> 16) | ((A0.u[3] + 0x8000u) & 0xFFFF0000u);
        af.u[2] = ((A1.u[0] + 0x8000u) >> 16) | ((A1.u[1] + 0x8000u) & 0xFFFF0000u);
        af.u[3] = ((A1.u[2] + 0x8000u) >> 16) | ((A1.u[3] + 0x8000u) & 0xFFFF0000u);
#pragma unroll
        for (int nf = 0; nf < 4; ++nf)
          acc[mf][nf] = __builtin_amdgcn_mfma_f32_16x16x32_bf16(
              af.v, bfrag[ks][nf], acc[mf][nf], 0, 0, 0);
      }
    }
  }

  // ---- epilogue: C/D layout col = lane&15, row = (lane>>4)*4 + reg ----
  float bv[4];
#pragma unroll
  for (int nf = 0; nf < 4; ++nf)
    bv[nf] = bias[n * BOUT + wave * 64 + nf * 16 + fr];

  float* yg = y + (size_t)m0 * XCOLS + n * BOUT + wave * 64;
#pragma unroll
  for (int mf = 0; mf < 4; ++mf) {
#pragma unroll
    for (int r = 0; r < 4; ++r) {
      float* yrow = yg + (size_t)(mf * 16 + fq * 4 + r) * XCOLS;
#pragma unroll
      for (int nf = 0; nf < 4; ++nf)
        __builtin_nontemporal_store(acc[mf][nf][r] + bv[nf], &yrow[nf * 16 + fr]);
    }
  }
}

// ---------------- fallback (ws too small): correct but slow fp32 ----------------
__global__ __launch_bounds__(256) void fallback_kernel(
    const float* __restrict__ x, const float* __restrict__ W,
    const float* __restrict__ b, float* __restrict__ y) {
  __shared__ float xrow[BIN];
  int row = blockIdx.x >> 3;
  int n   = blockIdx.x & 7;
  xrow[threadIdx.x] = x[(size_t)row * XCOLS + n * BIN + threadIdx.x];
  __syncthreads();
  const float* w = W + (size_t)(n * BOUT + threadIdx.x) * BIN;
  float s = b[n * BOUT + threadIdx.x];
  for (int i = 0; i < BIN; ++i) s += xrow[i] * w[i];
  y[(size_t)row * XCOLS + n * BIN + threadIdx.x] = s;
}

extern "C" void kernel_launch(void* const* d_in, const int* in_sizes, int n_in,
                              void* d_out, int out_size, void* d_ws, size_t ws_size,
                              hipStream_t stream) {
  const float* x = (const float*)d_in[0];
  const float* W = (const float*)d_in[1];
  const float* b = (const float*)d_in[2];
  float* y = (float*)d_out;

  const size_t ws_needed = (size_t)NBLK * KSTEPS * 2 * 16 * 64 * 8 * sizeof(unsigned short); // 1 MB
  if (ws_size >= ws_needed) {
    unsigned short* Wsz = (unsigned short*)d_ws;
    prep_w_kernel<<<2048, 256, 0, stream>>>(W, Wsz);
    blocklinear_kernel<<<(BATCH / BM) * NBLK, 256, 0, stream>>>(x, Wsz, b, y);
  } else {
    fallback_kernel<<<BATCH * NBLK, 256, 0, stream>>>(x, W, b, y);
  }
}